// Round 1
// baseline (100.790 us; speedup 1.0000x reference)
//
#include <hip/hip_runtime.h>
#include <math.h>

#define KSZ   17
#define PADR  8
#define FDIM  100
#define ODIM  180
#define HTOT  512
#define WTOT  512
#define TILE  16
#define LDSW  33          // 32-col tile padded to 33 to break bank aliasing
#define TEMPERATURE 20.0f
#define THRESHOLD   55.0f

// ---- order-preserving float<->uint encoding for atomic min/max ----
__device__ __forceinline__ unsigned int fenc(float f) {
    unsigned int u = __float_as_uint(f);
    return (u & 0x80000000u) ? ~u : (u | 0x80000000u);
}
__device__ __forceinline__ float fdec(unsigned int k) {
    unsigned int u = (k & 0x80000000u) ? (k ^ 0x80000000u) : ~k;
    return __uint_as_float(u);
}

__global__ __launch_bounds__(256) void filter_main(
    const float* __restrict__ x,
    const int*   __restrict__ freq,
    const int*   __restrict__ orient,
    const float* __restrict__ fb,
    float*       __restrict__ y,
    unsigned int* __restrict__ mm)
{
    __shared__ float tile[2 * TILE][LDSW];   // 32 rows x 33 floats = 4224 B

    const int bx = blockIdx.x, by = blockIdx.y;
    const int tid = threadIdx.x;
    const int tx = tid & (TILE - 1);
    const int ty = tid >> 4;

    // top-left corner of the padded 32x32 input region this block needs
    const int h0 = by * TILE - PADR;
    const int w0 = bx * TILE - PADR;

    // cooperative load of 32x32 region with zero padding outside the image
    for (int i = tid; i < 32 * 32; i += 256) {
        const int r = i >> 5, c = i & 31;
        const int gh = h0 + r, gw = w0 + c;
        float v = 0.f;
        if (gh >= 0 && gh < HTOT && gw >= 0 && gw < WTOT)
            v = x[gh * WTOT + gw];
        tile[r][c] = v;
    }
    __syncthreads();

    const int h = by * TILE + ty;
    const int w = bx * TILE + tx;
    const int pid = h * WTOT + w;

    int f0 = freq[pid] - 1;
    f0 = f0 < 0 ? 0 : (f0 > FDIM - 1 ? FDIM - 1 : f0);
    int o0 = orient[pid] - 1;
    o0 = o0 < 0 ? 0 : (o0 > ODIM - 1 ? ODIM - 1 : o0);

    const float* __restrict__ kf = fb + (size_t)(f0 * ODIM + o0) * (KSZ * KSZ);

    float acc = 0.f;
    #pragma unroll
    for (int kk = 0; kk < KSZ; ++kk) {
        const float* __restrict__ row = &tile[ty + kk][tx];
        const float* __restrict__ fr  = kf + kk * KSZ;
        #pragma unroll
        for (int l = 0; l < KSZ; ++l)
            acc = fmaf(row[l], fr[l], acc);
    }
    y[pid] = acc;

    // ---- block min/max reduce, then one atomic pair per block ----
    float mn = acc, mx = acc;
    #pragma unroll
    for (int off = 32; off > 0; off >>= 1) {
        mn = fminf(mn, __shfl_down(mn, off, 64));
        mx = fmaxf(mx, __shfl_down(mx, off, 64));
    }
    __shared__ float smn[4], smx[4];
    const int wid = tid >> 6, lane = tid & 63;
    if (lane == 0) { smn[wid] = mn; smx[wid] = mx; }
    __syncthreads();
    if (tid == 0) {
        float bmn = smn[0], bmx = smx[0];
        #pragma unroll
        for (int i = 1; i < 4; ++i) {
            bmn = fminf(bmn, smn[i]);
            bmx = fmaxf(bmx, smx[i]);
        }
        atomicMin(&mm[0], fenc(bmn));
        atomicMax(&mm[1], fenc(bmx));
    }
}

__global__ __launch_bounds__(256) void filter_final(
    float* __restrict__ y,
    const unsigned int* __restrict__ mm)
{
    const int i = blockIdx.x * 256 + threadIdx.x;
    const float ymin = fdec(mm[0]);
    const float ymax = fdec(mm[1]);
    const float rng  = fmaxf(ymax - ymin, 1e-8f);

    const float v  = y[i];
    const float o1 = 100.f * (v - ymin) / rng;                     // in [0,100]
    const float s  = 100.f / (1.f + expf(-(TEMPERATURE * (o1 * 0.01f - THRESHOLD * 0.01f))));

    // analytic post-sigmoid extrema: o1 hits exactly 0 and 100 at argmin/argmax
    const float smin = 100.f / (1.f + expf( 11.f));   // 100*sigmoid(-11)
    const float smax = 100.f / (1.f + expf(-9.f));    // 100*sigmoid(+9)
    const float srng = fmaxf(smax - smin, 1e-8f);

    y[i] = 100.f * (s - smin) / srng;
}

extern "C" void kernel_launch(void* const* d_in, const int* in_sizes, int n_in,
                              void* d_out, int out_size, void* d_ws, size_t ws_size,
                              hipStream_t stream) {
    const float* x      = (const float*)d_in[0];
    const int*   freq   = (const int*)d_in[1];
    const int*   orient = (const int*)d_in[2];
    const float* fb     = (const float*)d_in[3];
    float*       out    = (float*)d_out;           // doubles as y scratch
    unsigned int* mm    = (unsigned int*)d_ws;     // [0]=enc(min), [1]=enc(max)

    // init encoded min to 0xFFFFFFFF (= +inf key) and encoded max to 0
    hipMemsetAsync(mm, 0xFF, 4, stream);
    hipMemsetAsync((char*)d_ws + 4, 0x00, 4, stream);

    dim3 grid(WTOT / TILE, HTOT / TILE);           // 32 x 32 blocks
    filter_main<<<grid, 256, 0, stream>>>(x, freq, orient, fb, out, mm);

    filter_final<<<(HTOT * WTOT) / 256, 256, 0, stream>>>(out, mm);
}